// Round 2
// baseline (317.855 us; speedup 1.0000x reference)
//
#include <hip/hip_runtime.h>
#include <hip/hip_bf16.h>

#define N_USERS   100000
#define EMBED_DIM 128
#define N_EDGES   640000
#define ZERO_ROW  N_USERS          // embb row of zeros for padded edge slots
#define LOC_SHIFT 20               // perm entry: bits[19:0]=src id, bits[24:20]=dst&31
#define ID_MASK   0xFFFFF

typedef __bf16 bf16x8 __attribute__((ext_vector_type(8)));
typedef unsigned short u16x8 __attribute__((ext_vector_type(8)));
typedef float  f32x4  __attribute__((ext_vector_type(4)));

// ---- workspace layout (bytes) ----
// [0,          25,600,256)  embb   bf16 [100001][128] (row 100000 = zeros)
// [25,600,256, 26,000,256)  counts int  [100000]
// [26,000,256, 26,000,260)  total  int  [1]   (memset together with counts)
// [26,000,384, 26,400,384)  start  int  [100000]  (padded CSR starts, 4-aligned)
// [26,400,384, 26,800,384)  cursor int  [100000]
// [26,800,384, 30,560,384)  perm   int  [940000 max] (src|loc<<20 grouped by dst,
//                                                     padded to x4 with ZERO_ROW)
// [30,560,384, 30,593,152)  wlsw   bf16 [16384]  Wl in MFMA-fragment order
// [30,593,152, 30,625,920)  wrsw   bf16 [16384]  Wr in MFMA-fragment order
#define OFF_COUNTS 25600256
#define OFF_TOTAL  26000256
#define OFF_START  26000384
#define OFF_CURSOR 26400384
#define OFF_PERM   26800384
#define OFF_WLSW   30560384
#define OFF_WRSW   30593152

__device__ __forceinline__ unsigned short f2bf_rne(float f) {
    union { float f; unsigned u; } c; c.f = f;
    unsigned u = c.u + 0x7fffu + ((c.u >> 16) & 1u);
    return (unsigned short)(u >> 16);
}
__device__ __forceinline__ float bf2f_lo(unsigned u) {
    union { float f; unsigned u; } c; c.u = u << 16;
    return c.f;
}
__device__ __forceinline__ float bf2f_hi(unsigned u) {
    union { float f; unsigned u; } c; c.u = u & 0xffff0000u;
    return c.f;
}

// Convert emb -> embb (bf16), zero-row, dst histogram, and write W_l/W_r in
// MFMA B-fragment order:  wsw[((jt*4+kt)*64 + lane)*8 + j]
//   = W[jt*16 + (lane&15)][kt*32 + (lane>>4)*8 + j]
// counts/total pre-zeroed by hipMemsetAsync.  grid: 6250 x 256
__global__ __launch_bounds__(256) void k_init(const float* __restrict__ emb,
                                              const float* __restrict__ Wl,
                                              const float* __restrict__ Wr,
                                              const int* __restrict__ dst,
                                              unsigned short* __restrict__ embb,
                                              int* __restrict__ counts,
                                              unsigned short* __restrict__ wlsw,
                                              unsigned short* __restrict__ wrsw) {
    int i = blockIdx.x * 256 + threadIdx.x;
    if (i < 2048) {    // 2048 threads x 8 elems = 16384 = one W table
        int li = i & 63;            // lane
        int kt = (i >> 6) & 3;
        int jt = i >> 8;            // 0..7
        int row  = jt * 16 + (li & 15);
        int colb = kt * 32 + ((li >> 4) << 3);
        const float4* pl = (const float4*)(Wl + row * 128 + colb);
        const float4* pr = (const float4*)(Wr + row * 128 + colb);
        float4 l0 = pl[0], l1 = pl[1];
        float4 r0 = pr[0], r1 = pr[1];
        int o = i * 8;
        wlsw[o+0] = f2bf_rne(l0.x); wlsw[o+1] = f2bf_rne(l0.y);
        wlsw[o+2] = f2bf_rne(l0.z); wlsw[o+3] = f2bf_rne(l0.w);
        wlsw[o+4] = f2bf_rne(l1.x); wlsw[o+5] = f2bf_rne(l1.y);
        wlsw[o+6] = f2bf_rne(l1.z); wlsw[o+7] = f2bf_rne(l1.w);
        wrsw[o+0] = f2bf_rne(r0.x); wrsw[o+1] = f2bf_rne(r0.y);
        wrsw[o+2] = f2bf_rne(r0.z); wrsw[o+3] = f2bf_rne(r0.w);
        wrsw[o+4] = f2bf_rne(r1.x); wrsw[o+5] = f2bf_rne(r1.y);
        wrsw[o+6] = f2bf_rne(r1.z); wrsw[o+7] = f2bf_rne(r1.w);
    }
    // zero row at index N_USERS: 128 bf16 = 256 B = exactly 16 int4.
    if (i < 16) {
        int4 z = {0, 0, 0, 0};
        ((int4*)(embb + (size_t)ZERO_ROW * EMBED_DIM))[i] = z;
    }
    // emb -> embb, 8 floats per thread
    float4 a = ((const float4*)emb)[i * 2 + 0];
    float4 b = ((const float4*)emb)[i * 2 + 1];
    int4 p;
    p.x = (int)f2bf_rne(a.x) | ((int)f2bf_rne(a.y) << 16);
    p.y = (int)f2bf_rne(a.z) | ((int)f2bf_rne(a.w) << 16);
    p.z = (int)f2bf_rne(b.x) | ((int)f2bf_rne(b.y) << 16);
    p.w = (int)f2bf_rne(b.z) | ((int)f2bf_rne(b.w) << 16);
    ((int4*)embb)[i] = p;
    // dst histogram (overlaps with the streaming conversion)
    if (i < N_EDGES) atomicAdd(&counts[dst[i]], 1);
}

// Exclusive allocation of contiguous per-node regions, PADDED to multiples
// of 4; fill pad slots of perm with ZERO_ROW|loc (group stays homogeneous).
// grid: 98 x 256
__global__ __launch_bounds__(256) void k_alloc(const int* __restrict__ counts,
                                               int* __restrict__ start,
                                               int* __restrict__ cursor,
                                               int* __restrict__ total,
                                               int* __restrict__ perm) {
    int i    = blockIdx.x * 256 + threadIdx.x;
    int lane = threadIdx.x & 63;
    int wv   = threadIdx.x >> 6;
    int4 c4 = {0, 0, 0, 0};
    if (i < 25000) c4 = ((const int4*)counts)[i];
    int4 p4;                       // padded counts
    p4.x = (c4.x + 3) & ~3;
    p4.y = (c4.y + 3) & ~3;
    p4.z = (c4.z + 3) & ~3;
    p4.w = (c4.w + 3) & ~3;
    int csum = p4.x + p4.y + p4.z + p4.w;
    int pre = csum;
#pragma unroll
    for (int d = 1; d < 64; d <<= 1) {
        int v = __shfl_up(pre, d);
        if (lane >= d) pre += v;
    }
    __shared__ int swv[4];
    __shared__ int sgbase;
    if (lane == 63) swv[wv] = pre;
    __syncthreads();
    if (threadIdx.x == 0)
        sgbase = atomicAdd(total, swv[0] + swv[1] + swv[2] + swv[3]);
    __syncthreads();
    int waveoff = 0;
    for (int w = 0; w < wv; w++) waveoff += swv[w];
    int base = sgbase + waveoff + (pre - csum);
    if (i < 25000) {
        int4 s;
        s.x = base;
        s.y = s.x + p4.x;
        s.z = s.y + p4.y;
        s.w = s.z + p4.z;
        ((int4*)start)[i]  = s;
        ((int4*)cursor)[i] = s;
        int n0 = i * 4;
        int zx = ZERO_ROW | (((n0 + 0) & 31) << LOC_SHIFT);
        int zy = ZERO_ROW | (((n0 + 1) & 31) << LOC_SHIFT);
        int zz = ZERO_ROW | (((n0 + 2) & 31) << LOC_SHIFT);
        int zw = ZERO_ROW | (((n0 + 3) & 31) << LOC_SHIFT);
        for (int k = c4.x; k < p4.x; k++) perm[s.x + k] = zx;
        for (int k = c4.y; k < p4.y; k++) perm[s.y + k] = zy;
        for (int k = c4.z; k < p4.z; k++) perm[s.z + k] = zz;
        for (int k = c4.w; k < p4.w; k++) perm[s.w + k] = zw;
    }
}

// Scatter edge src-ids (with packed dst-local slot) into dst-grouped buckets.
// grid: 2500 x 256
__global__ __launch_bounds__(256) void k_perm(const int* __restrict__ src,
                                              const int* __restrict__ dst,
                                              int* __restrict__ cursor,
                                              int* __restrict__ perm) {
    int e = blockIdx.x * 256 + threadIdx.x;
    if (e < N_EDGES) {
        int d = dst[e];
        int pos = atomicAdd(&cursor[d], 1);
        perm[pos] = src[e] | ((d & 31) << LOC_SHIFT);
    }
}

// FUSED aggregate + matmul: block = 32 nodes x 128 cols, 4 waves.
// Phase 1 (gather): BLOCK-COOPERATIVE CSR stream. The block's 32 nodes own a
//   contiguous, x4-padded perm range; every int4 group is homogeneous (one
//   node) and carries its dst-local slot in bits[24:20]. The 4 waves stream
//   groups round-robin (g = wave, g += 4) -- iterations fully independent, so
//   the compiler pipelines a continuous load stream with no per-node windup
//   and perfect intra-block balance. Each group: 4 coalesced 256B row-loads,
//   tree-sum, 2x ds_add_f32 into s_acc[32][132] fp32 (pad 132 -> 2-way
//   banking, free; atomic addresses 2-way aliased, free).
// Phase 2 (MFMA): A-fragments built straight from s_acc (x 1/deg, rne->bf16,
//   same rounding points as before); self rows from se; W from the
//   pre-swizzled tables (base + lane*16B, L2-hot).
// LDS 25.6 KB -> 6 blocks/CU (24 waves) with __launch_bounds__(256,6).
// grid: 3125 x 256
#define LDS_S  136
#define SACC_S 132
__global__ __launch_bounds__(256, 6) void k_fused(const unsigned short* __restrict__ embb,
                                                  const int* __restrict__ start,
                                                  const int* __restrict__ counts,
                                                  const int* __restrict__ perm,
                                                  const unsigned short* __restrict__ wlsw,
                                                  const unsigned short* __restrict__ wrsw,
                                                  const float* __restrict__ bl,
                                                  float* __restrict__ out) {
    __shared__ float          s_acc[32 * SACC_S];   // 16,896 B fp32 accumulators
    __shared__ unsigned short se[32 * LDS_S];       //  8,704 B self rows (bf16)
    int tid  = threadIdx.x;
    int wave = tid >> 6;
    int lane = tid & 63;
    int quad = lane >> 4;      // 0..3
    int m    = lane & 15;
    int node0 = blockIdx.x * 32;
    int off   = lane * 2;      // dword column this lane owns (shorts / floats)

    // ---- issue self-slab loads early: 2 x 8 KB contiguous ----
    const int4* eslab = (const int4*)(embb + (size_t)node0 * EMBED_DIM);
    int4 ve0 = eslab[tid];
    int4 ve1 = eslab[256 + tid];

    // ---- per-lane degree for the MFMA-phase divide (L2-hot, issue early) ----
    int cR0 = counts[node0 + m];
    int cR1 = counts[node0 + 16 + m];

    // ---- zero accumulators, then barrier before any atomics ----
    for (int z = tid; z < 32 * SACC_S; z += 256) s_acc[z] = 0.0f;
    __syncthreads();

    // ---- phase 1: cooperative CSR stream ----
    int gbase = start[node0];
    int nL    = node0 + 31;
    int gend  = start[nL] + ((counts[nL] + 3) & ~3);
    int ngroups = (gend - gbase) >> 2;
    const int4* gp = (const int4*)(perm + gbase);
    const unsigned short* ep = embb;
#pragma unroll 2
    for (int g = wave; g < ngroups; g += 4) {
        int4 q4 = gp[g];
        int loc = (q4.x >> LOC_SHIFT) & 31;
        unsigned a0 = *(const unsigned*)(ep + (size_t)(q4.x & ID_MASK) * EMBED_DIM + off);
        unsigned a1 = *(const unsigned*)(ep + (size_t)(q4.y & ID_MASK) * EMBED_DIM + off);
        unsigned a2 = *(const unsigned*)(ep + (size_t)(q4.z & ID_MASK) * EMBED_DIM + off);
        unsigned a3 = *(const unsigned*)(ep + (size_t)(q4.w & ID_MASK) * EMBED_DIM + off);
        float lo = (bf2f_lo(a0) + bf2f_lo(a1)) + (bf2f_lo(a2) + bf2f_lo(a3));
        float hi = (bf2f_hi(a0) + bf2f_hi(a1)) + (bf2f_hi(a2) + bf2f_hi(a3));
        atomicAdd(&s_acc[loc * SACC_S + off],     lo);
        atomicAdd(&s_acc[loc * SACC_S + off + 1], hi);
    }

    // ---- write self slab to LDS (loads issued at kernel top) ----
    {
        int g = tid, row = g >> 4, c = g & 15;
        *(int4*)(se + row * LDS_S + c * 8) = ve0;
        g = 256 + tid; row = g >> 4; c = g & 15;
        *(int4*)(se + row * LDS_S + c * 8) = ve1;
    }

    // ---- W fragments from swizzled tables (overlap the barrier wait) ----
    int jt0 = wave * 2;
    bf16x8 wl[2][4], wr[2][4];
#pragma unroll
    for (int jj = 0; jj < 2; jj++) {
#pragma unroll
        for (int kt = 0; kt < 4; kt++) {
            size_t o = (size_t)((((jt0 + jj) * 4 + kt) * 64 + lane)) * 8;
            wl[jj][kt] = *(const bf16x8*)((const __bf16*)wlsw + o);
            wr[jj][kt] = *(const bf16x8*)((const __bf16*)wrsw + o);
        }
    }
    float bias[2];
    bias[0] = bl[(jt0 + 0) * 16 + m];
    bias[1] = bl[(jt0 + 1) * 16 + m];
    float inv[2];
    inv[0] = (cR0 > 0) ? 1.0f / (float)cR0 : 0.0f;
    inv[1] = (cR1 > 0) ? 1.0f / (float)cR1 : 0.0f;

    __syncthreads();   // all waves' ds_add_f32 drained

    // ---- phase 2: A-fragments from s_acc (x inv, rne->bf16), ef from se ----
#pragma unroll
    for (int rt = 0; rt < 2; rt++) {
        float iv = inv[rt];
        bf16x8 af[4], ef[4];
#pragma unroll
        for (int kt = 0; kt < 4; kt++) {
            const float* pr = s_acc + (rt * 16 + m) * SACC_S + kt * 32 + quad * 8;
            f32x4 x0 = *(const f32x4*)pr;
            f32x4 x1 = *(const f32x4*)(pr + 4);
            u16x8 ua;
            ua[0] = f2bf_rne(x0[0] * iv); ua[1] = f2bf_rne(x0[1] * iv);
            ua[2] = f2bf_rne(x0[2] * iv); ua[3] = f2bf_rne(x0[3] * iv);
            ua[4] = f2bf_rne(x1[0] * iv); ua[5] = f2bf_rne(x1[1] * iv);
            ua[6] = f2bf_rne(x1[2] * iv); ua[7] = f2bf_rne(x1[3] * iv);
            af[kt] = *(bf16x8*)&ua;
            int o = (rt * 16 + m) * LDS_S + kt * 32 + quad * 8;
            ef[kt] = *(const bf16x8*)(se + o);
        }
        f32x4 acc[2] = {{0.f,0.f,0.f,0.f}, {0.f,0.f,0.f,0.f}};
#pragma unroll
        for (int kt = 0; kt < 4; kt++) {
#pragma unroll
            for (int jj = 0; jj < 2; jj++) {
                acc[jj] = __builtin_amdgcn_mfma_f32_16x16x32_bf16(af[kt], wl[jj][kt], acc[jj], 0, 0, 0);
                acc[jj] = __builtin_amdgcn_mfma_f32_16x16x32_bf16(ef[kt], wr[jj][kt], acc[jj], 0, 0, 0);
            }
        }
        // C/D layout: col = lane&15, row = quad*4 + reg
#pragma unroll
        for (int jj = 0; jj < 2; jj++) {
#pragma unroll
            for (int r = 0; r < 4; r++) {
                int orow = node0 + rt * 16 + quad * 4 + r;
                out[(size_t)orow * EMBED_DIM + (jt0 + jj) * 16 + m] = acc[jj][r] + bias[jj];
            }
        }
    }
}

extern "C" void kernel_launch(void* const* d_in, const int* in_sizes, int n_in,
                              void* d_out, int out_size, void* d_ws, size_t ws_size,
                              hipStream_t stream) {
    const float* emb = (const float*)d_in[0];
    const float* Wl  = (const float*)d_in[1];
    const float* bl  = (const float*)d_in[2];
    const float* Wr  = (const float*)d_in[3];
    const int*   src = (const int*)d_in[4];
    const int*   dst = (const int*)d_in[5];
    float* out = (float*)d_out;

    char* ws = (char*)d_ws;
    unsigned short* embb   = (unsigned short*)ws;
    int*            counts = (int*)(ws + OFF_COUNTS);
    int*            total  = (int*)(ws + OFF_TOTAL);
    int*            start  = (int*)(ws + OFF_START);
    int*            cursor = (int*)(ws + OFF_CURSOR);
    int*            perm   = (int*)(ws + OFF_PERM);
    unsigned short* wlsw   = (unsigned short*)(ws + OFF_WLSW);
    unsigned short* wrsw   = (unsigned short*)(ws + OFF_WRSW);

    // zero counts + total (graph-capturable memset node)
    hipMemsetAsync(ws + OFF_COUNTS, 0, (OFF_TOTAL - OFF_COUNTS) + 4, stream);

    k_init<<<6250, 256, 0, stream>>>(emb, Wl, Wr, dst, embb, counts, wlsw, wrsw);
    k_alloc<<<98, 256, 0, stream>>>(counts, start, cursor, total, perm);
    k_perm<<<2500, 256, 0, stream>>>(src, dst, cursor, perm);
    k_fused<<<3125, 256, 0, stream>>>(embb, start, counts, perm, wlsw, wrsw, bl, out);
}

// Round 3
// 228.986 us; speedup vs baseline: 1.3881x; 1.3881x over previous
//
#include <hip/hip_runtime.h>
#include <hip/hip_bf16.h>

#define N_USERS   100000
#define EMBED_DIM 128
#define N_EDGES   640000
#define ZERO_ROW  N_USERS          // embb row of zeros for padded edge slots
#define LOC_SHIFT 20               // perm entry: bits[19:0]=src id, bits[24:20]=dst&31
#define ID_MASK   0xFFFFF

typedef __bf16 bf16x8 __attribute__((ext_vector_type(8)));
typedef unsigned short u16x8 __attribute__((ext_vector_type(8)));
typedef float  f32x4  __attribute__((ext_vector_type(4)));

// ---- workspace layout (bytes) ----
// [0,          25,600,256)  embb   bf16 [100001][128] (row 100000 = zeros)
// [25,600,256, 26,000,256)  counts int  [100000]
// [26,000,256, 26,000,260)  total  int  [1]   (memset together with counts)
// [26,000,384, 26,400,384)  start  int  [100000]  (padded CSR starts, 4-aligned)
// [26,400,384, 26,800,384)  cursor int  [100000]
// [26,800,384, 30,560,384)  perm   int  [940000 max] (src|loc<<20 grouped by dst,
//                                                     padded to x4 with ZERO_ROW)
// [30,560,384, 30,593,152)  wlsw   bf16 [16384]  Wl in MFMA-fragment order
// [30,593,152, 30,625,920)  wrsw   bf16 [16384]  Wr in MFMA-fragment order
#define OFF_COUNTS 25600256
#define OFF_TOTAL  26000256
#define OFF_START  26000384
#define OFF_CURSOR 26400384
#define OFF_PERM   26800384
#define OFF_WLSW   30560384
#define OFF_WRSW   30593152

__device__ __forceinline__ unsigned short f2bf_rne(float f) {
    union { float f; unsigned u; } c; c.f = f;
    unsigned u = c.u + 0x7fffu + ((c.u >> 16) & 1u);
    return (unsigned short)(u >> 16);
}
__device__ __forceinline__ float bf2f_lo(unsigned u) {
    union { float f; unsigned u; } c; c.u = u << 16;
    return c.f;
}
__device__ __forceinline__ float bf2f_hi(unsigned u) {
    union { float f; unsigned u; } c; c.u = u & 0xffff0000u;
    return c.f;
}

// Convert emb -> embb (bf16), zero-row, dst histogram, and write W_l/W_r in
// MFMA B-fragment order:  wsw[((jt*4+kt)*64 + lane)*8 + j]
//   = W[jt*16 + (lane&15)][kt*32 + (lane>>4)*8 + j]
// counts/total pre-zeroed by hipMemsetAsync.  grid: 6250 x 256
__global__ __launch_bounds__(256) void k_init(const float* __restrict__ emb,
                                              const float* __restrict__ Wl,
                                              const float* __restrict__ Wr,
                                              const int* __restrict__ dst,
                                              unsigned short* __restrict__ embb,
                                              int* __restrict__ counts,
                                              unsigned short* __restrict__ wlsw,
                                              unsigned short* __restrict__ wrsw) {
    int i = blockIdx.x * 256 + threadIdx.x;
    if (i < 2048) {    // 2048 threads x 8 elems = 16384 = one W table
        int li = i & 63;            // lane
        int kt = (i >> 6) & 3;
        int jt = i >> 8;            // 0..7
        int row  = jt * 16 + (li & 15);
        int colb = kt * 32 + ((li >> 4) << 3);
        const float4* pl = (const float4*)(Wl + row * 128 + colb);
        const float4* pr = (const float4*)(Wr + row * 128 + colb);
        float4 l0 = pl[0], l1 = pl[1];
        float4 r0 = pr[0], r1 = pr[1];
        int o = i * 8;
        wlsw[o+0] = f2bf_rne(l0.x); wlsw[o+1] = f2bf_rne(l0.y);
        wlsw[o+2] = f2bf_rne(l0.z); wlsw[o+3] = f2bf_rne(l0.w);
        wlsw[o+4] = f2bf_rne(l1.x); wlsw[o+5] = f2bf_rne(l1.y);
        wlsw[o+6] = f2bf_rne(l1.z); wlsw[o+7] = f2bf_rne(l1.w);
        wrsw[o+0] = f2bf_rne(r0.x); wrsw[o+1] = f2bf_rne(r0.y);
        wrsw[o+2] = f2bf_rne(r0.z); wrsw[o+3] = f2bf_rne(r0.w);
        wrsw[o+4] = f2bf_rne(r1.x); wrsw[o+5] = f2bf_rne(r1.y);
        wrsw[o+6] = f2bf_rne(r1.z); wrsw[o+7] = f2bf_rne(r1.w);
    }
    // zero row at index N_USERS: 128 bf16 = 256 B = exactly 16 int4.
    if (i < 16) {
        int4 z = {0, 0, 0, 0};
        ((int4*)(embb + (size_t)ZERO_ROW * EMBED_DIM))[i] = z;
    }
    // emb -> embb, 8 floats per thread
    float4 a = ((const float4*)emb)[i * 2 + 0];
    float4 b = ((const float4*)emb)[i * 2 + 1];
    int4 p;
    p.x = (int)f2bf_rne(a.x) | ((int)f2bf_rne(a.y) << 16);
    p.y = (int)f2bf_rne(a.z) | ((int)f2bf_rne(a.w) << 16);
    p.z = (int)f2bf_rne(b.x) | ((int)f2bf_rne(b.y) << 16);
    p.w = (int)f2bf_rne(b.z) | ((int)f2bf_rne(b.w) << 16);
    ((int4*)embb)[i] = p;
    // dst histogram (overlaps with the streaming conversion)
    if (i < N_EDGES) atomicAdd(&counts[dst[i]], 1);
}

// Exclusive allocation of contiguous per-node regions, PADDED to multiples
// of 4; fill pad slots of perm with ZERO_ROW|loc (group stays homogeneous).
// grid: 98 x 256
__global__ __launch_bounds__(256) void k_alloc(const int* __restrict__ counts,
                                               int* __restrict__ start,
                                               int* __restrict__ cursor,
                                               int* __restrict__ total,
                                               int* __restrict__ perm) {
    int i    = blockIdx.x * 256 + threadIdx.x;
    int lane = threadIdx.x & 63;
    int wv   = threadIdx.x >> 6;
    int4 c4 = {0, 0, 0, 0};
    if (i < 25000) c4 = ((const int4*)counts)[i];
    int4 p4;                       // padded counts
    p4.x = (c4.x + 3) & ~3;
    p4.y = (c4.y + 3) & ~3;
    p4.z = (c4.z + 3) & ~3;
    p4.w = (c4.w + 3) & ~3;
    int csum = p4.x + p4.y + p4.z + p4.w;
    int pre = csum;
#pragma unroll
    for (int d = 1; d < 64; d <<= 1) {
        int v = __shfl_up(pre, d);
        if (lane >= d) pre += v;
    }
    __shared__ int swv[4];
    __shared__ int sgbase;
    if (lane == 63) swv[wv] = pre;
    __syncthreads();
    if (threadIdx.x == 0)
        sgbase = atomicAdd(total, swv[0] + swv[1] + swv[2] + swv[3]);
    __syncthreads();
    int waveoff = 0;
    for (int w = 0; w < wv; w++) waveoff += swv[w];
    int base = sgbase + waveoff + (pre - csum);
    if (i < 25000) {
        int4 s;
        s.x = base;
        s.y = s.x + p4.x;
        s.z = s.y + p4.y;
        s.w = s.z + p4.z;
        ((int4*)start)[i]  = s;
        ((int4*)cursor)[i] = s;
        int n0 = i * 4;
        int zx = ZERO_ROW | (((n0 + 0) & 31) << LOC_SHIFT);
        int zy = ZERO_ROW | (((n0 + 1) & 31) << LOC_SHIFT);
        int zz = ZERO_ROW | (((n0 + 2) & 31) << LOC_SHIFT);
        int zw = ZERO_ROW | (((n0 + 3) & 31) << LOC_SHIFT);
        for (int k = c4.x; k < p4.x; k++) perm[s.x + k] = zx;
        for (int k = c4.y; k < p4.y; k++) perm[s.y + k] = zy;
        for (int k = c4.z; k < p4.z; k++) perm[s.z + k] = zz;
        for (int k = c4.w; k < p4.w; k++) perm[s.w + k] = zw;
    }
}

// Scatter edge src-ids (with packed dst-local slot) into dst-grouped buckets.
// grid: 2500 x 256
__global__ __launch_bounds__(256) void k_perm(const int* __restrict__ src,
                                              const int* __restrict__ dst,
                                              int* __restrict__ cursor,
                                              int* __restrict__ perm) {
    int e = blockIdx.x * 256 + threadIdx.x;
    if (e < N_EDGES) {
        int d = dst[e];
        int pos = atomicAdd(&cursor[d], 1);
        perm[pos] = src[e] | ((d & 31) << LOC_SHIFT);
    }
}

// FUSED aggregate + matmul: block = 32 nodes x 128 cols, 4 waves.
// Phase 1 (gather): FLAT per-wave CSR stream, NO ATOMICS. Each wave owns 8
//   consecutive nodes whose padded groups form ONE contiguous perm range.
//   The wave streams int4 groups (wave-uniform broadcast load; every group
//   homogeneous, dst-local slot in bits[24:20]); the node boundary is
//   wave-uniform, so the running fp32 sum is flushed with a plain ds_write
//   when loc changes -- exactly one LDS write per node, zero atomics, zero
//   per-node windup (iterations' loads are address-independent -> the
//   compiler pipelines a continuous load stream).
//   Each wave pre-zeroes only its OWN 8 rows -> no barrier before gather;
//   the single __syncthreads of the kernel sits between gather and MFMA.
// Phase 2 (MFMA): af built from s_acc (x 1/deg, rne->bf16 -- same rounding
//   as the verified rounds); ef loaded DIRECTLY from embb (L3-resident:
//   gather touches 99.8% of rows; each wave covers its rows' full 64B
//   lines) -- the se LDS slab and its staging registers are gone.
// LDS = 16.9 KB only; no launch_bounds register clamp (round-2 lesson:
// FP LDS atomics + reg clamp => CAS loops + scratch spill).
// grid: 3125 x 256
#define SACC_S 132
__global__ __launch_bounds__(256) void k_fused(const unsigned short* __restrict__ embb,
                                               const int* __restrict__ start,
                                               const int* __restrict__ counts,
                                               const int* __restrict__ perm,
                                               const unsigned short* __restrict__ wlsw,
                                               const unsigned short* __restrict__ wrsw,
                                               const float* __restrict__ bl,
                                               float* __restrict__ out) {
    __shared__ float s_acc[32 * SACC_S];   // 16,896 B fp32 accumulators
    int tid  = threadIdx.x;
    int wave = tid >> 6;
    int lane = tid & 63;
    int quad = lane >> 4;      // 0..3
    int m    = lane & 15;
    int node0 = blockIdx.x * 32;
    int off   = lane * 2;      // dword column this lane owns

    // ---- per-lane degree for the phase-2 divide (L2-hot, issue early) ----
    int cR0 = counts[node0 + m];
    int cR1 = counts[node0 + 16 + m];

    // ---- wave's flat group range over its 8 nodes ----
    int n0 = node0 + wave * 8;
    int nL = n0 + 7;
    int gS = start[n0] >> 2;
    int gE = (start[nL] + ((counts[nL] + 3) & ~3)) >> 2;

    // ---- zero OWN 8 rows (cols 0..127); no cross-wave deps -> no barrier ----
    float2 z2 = {0.f, 0.f};
#pragma unroll
    for (int r = 0; r < 8; r++)
        *(float2*)(s_acc + (wave * 8 + r) * SACC_S + off) = z2;

    // ---- phase 1: flat stream, flush-on-boundary ----
    const int4* gp = (const int4*)perm;
    const unsigned short* ep = embb;
    float lo = 0.f, hi = 0.f;
    int cur = -1;
#pragma unroll 2
    for (int g = gS; g < gE; g++) {
        int4 q4 = gp[g];                       // wave-uniform broadcast
        int loc = (q4.x >> LOC_SHIFT) & 31;    // wave-uniform
        if (loc != cur) {
            if (cur >= 0) {
                float2 v = {lo, hi};
                *(float2*)(s_acc + cur * SACC_S + off) = v;
            }
            lo = 0.f; hi = 0.f; cur = loc;
        }
        unsigned a0 = *(const unsigned*)(ep + (size_t)(q4.x & ID_MASK) * EMBED_DIM + off);
        unsigned a1 = *(const unsigned*)(ep + (size_t)(q4.y & ID_MASK) * EMBED_DIM + off);
        unsigned a2 = *(const unsigned*)(ep + (size_t)(q4.z & ID_MASK) * EMBED_DIM + off);
        unsigned a3 = *(const unsigned*)(ep + (size_t)(q4.w & ID_MASK) * EMBED_DIM + off);
        lo += (bf2f_lo(a0) + bf2f_lo(a1)) + (bf2f_lo(a2) + bf2f_lo(a3));
        hi += (bf2f_hi(a0) + bf2f_hi(a1)) + (bf2f_hi(a2) + bf2f_hi(a3));
    }
    if (cur >= 0) {
        float2 v = {lo, hi};
        *(float2*)(s_acc + cur * SACC_S + off) = v;
    }

    // ---- W fragments from swizzled tables (overlap the barrier wait) ----
    int jt0 = wave * 2;
    bf16x8 wl[2][4], wr[2][4];
#pragma unroll
    for (int jj = 0; jj < 2; jj++) {
#pragma unroll
        for (int kt = 0; kt < 4; kt++) {
            size_t o = (size_t)((((jt0 + jj) * 4 + kt) * 64 + lane)) * 8;
            wl[jj][kt] = *(const bf16x8*)((const __bf16*)wlsw + o);
            wr[jj][kt] = *(const bf16x8*)((const __bf16*)wrsw + o);
        }
    }
    float bias[2];
    bias[0] = bl[(jt0 + 0) * 16 + m];
    bias[1] = bl[(jt0 + 1) * 16 + m];
    float inv[2];
    inv[0] = (cR0 > 0) ? 1.0f / (float)cR0 : 0.0f;
    inv[1] = (cR1 > 0) ? 1.0f / (float)cR1 : 0.0f;

    __syncthreads();   // all waves' flushes visible

    // ---- phase 2: af from s_acc (x inv, rne->bf16); ef straight from embb ----
#pragma unroll
    for (int rt = 0; rt < 2; rt++) {
        float iv = inv[rt];
        bf16x8 af[4], ef[4];
#pragma unroll
        for (int kt = 0; kt < 4; kt++) {
            const float* pr = s_acc + (rt * 16 + m) * SACC_S + kt * 32 + quad * 8;
            f32x4 x0 = *(const f32x4*)pr;
            f32x4 x1 = *(const f32x4*)(pr + 4);
            u16x8 ua;
            ua[0] = f2bf_rne(x0[0] * iv); ua[1] = f2bf_rne(x0[1] * iv);
            ua[2] = f2bf_rne(x0[2] * iv); ua[3] = f2bf_rne(x0[3] * iv);
            ua[4] = f2bf_rne(x1[0] * iv); ua[5] = f2bf_rne(x1[1] * iv);
            ua[6] = f2bf_rne(x1[2] * iv); ua[7] = f2bf_rne(x1[3] * iv);
            af[kt] = *(bf16x8*)&ua;
            ef[kt] = *(const bf16x8*)(embb + (size_t)(node0 + rt * 16 + m) * EMBED_DIM
                                      + kt * 32 + quad * 8);
        }
        f32x4 acc[2] = {{0.f,0.f,0.f,0.f}, {0.f,0.f,0.f,0.f}};
#pragma unroll
        for (int kt = 0; kt < 4; kt++) {
#pragma unroll
            for (int jj = 0; jj < 2; jj++) {
                acc[jj] = __builtin_amdgcn_mfma_f32_16x16x32_bf16(af[kt], wl[jj][kt], acc[jj], 0, 0, 0);
                acc[jj] = __builtin_amdgcn_mfma_f32_16x16x32_bf16(ef[kt], wr[jj][kt], acc[jj], 0, 0, 0);
            }
        }
        // C/D layout: col = lane&15, row = quad*4 + reg
#pragma unroll
        for (int jj = 0; jj < 2; jj++) {
#pragma unroll
            for (int r = 0; r < 4; r++) {
                int orow = node0 + rt * 16 + quad * 4 + r;
                out[(size_t)orow * EMBED_DIM + (jt0 + jj) * 16 + m] = acc[jj][r] + bias[jj];
            }
        }
    }
}

extern "C" void kernel_launch(void* const* d_in, const int* in_sizes, int n_in,
                              void* d_out, int out_size, void* d_ws, size_t ws_size,
                              hipStream_t stream) {
    const float* emb = (const float*)d_in[0];
    const float* Wl  = (const float*)d_in[1];
    const float* bl  = (const float*)d_in[2];
    const float* Wr  = (const float*)d_in[3];
    const int*   src = (const int*)d_in[4];
    const int*   dst = (const int*)d_in[5];
    float* out = (float*)d_out;

    char* ws = (char*)d_ws;
    unsigned short* embb   = (unsigned short*)ws;
    int*            counts = (int*)(ws + OFF_COUNTS);
    int*            total  = (int*)(ws + OFF_TOTAL);
    int*            start  = (int*)(ws + OFF_START);
    int*            cursor = (int*)(ws + OFF_CURSOR);
    int*            perm   = (int*)(ws + OFF_PERM);
    unsigned short* wlsw   = (unsigned short*)(ws + OFF_WLSW);
    unsigned short* wrsw   = (unsigned short*)(ws + OFF_WRSW);

    // zero counts + total (graph-capturable memset node)
    hipMemsetAsync(ws + OFF_COUNTS, 0, (OFF_TOTAL - OFF_COUNTS) + 4, stream);

    k_init<<<6250, 256, 0, stream>>>(emb, Wl, Wr, dst, embb, counts, wlsw, wrsw);
    k_alloc<<<98, 256, 0, stream>>>(counts, start, cursor, total, perm);
    k_perm<<<2500, 256, 0, stream>>>(src, dst, cursor, perm);
    k_fused<<<3125, 256, 0, stream>>>(embb, start, counts, perm, wlsw, wrsw, bl, out);
}